// Round 1
// baseline (148.330 us; speedup 1.0000x reference)
//
#include <hip/hip_runtime.h>
#include <hip/hip_fp16.h>

#define NH 12
#define BSZ 8
#define NSEQ 1024
#define EDIM 768
#define DH 64

typedef _Float16 f16;
typedef f16 half8 __attribute__((ext_vector_type(8)));
typedef f16 half4 __attribute__((ext_vector_type(4)));
typedef float f32x4 __attribute__((ext_vector_type(4)));

// ---------------- fp32 -> fp16 convert ----------------
__global__ void cvt_kernel(const float* __restrict__ s, f16* __restrict__ d, int n) {
    int i = (blockIdx.x * blockDim.x + threadIdx.x) * 4;
    if (i < n) {
        float4 v = *(const float4*)(s + i);
        half4 o = { (f16)v.x, (f16)v.y, (f16)v.z, (f16)v.w };
        *(half4*)(d + i) = o;
    }
}

// ---------------- GEMM: C[m][c] = sum_k A[m][k]*W[c][k] + bias[c] ----------------
// MODE 0: QKV (scatter to q/k/v fp16 buffers, skip fully-masked head blocks)
// MODE 1: proj (fp32 output)
template<int MODE>
__global__ __launch_bounds__(256) void gemm_kernel(
    const f16* __restrict__ A,    // [M][K] fp16
    const f16* __restrict__ Wt,   // [NC][K] fp16
    const float* __restrict__ bias, // [NC]
    f16* __restrict__ qbuf, f16* __restrict__ kbuf, f16* __restrict__ vbuf,
    float* __restrict__ outp,
    const int* __restrict__ activep,
    int K, int NC)
{
    __shared__ __align__(16) f16 Ah[128][40];
    __shared__ __align__(16) f16 Bh[128][40];

    const int tid = threadIdx.x;
    const int c0 = blockIdx.x * 128;
    const int m0 = blockIdx.y * 128;
    const int ah = *activep;
    if (MODE == 0) {
        int hb = (c0 % EDIM) >> 6;   // first head covered by this col-block
        if (hb >= ah) return;        // both heads masked -> qkv never read
    }
    const int lane = tid & 63;
    const int wid  = tid >> 6;
    const int wr = wid >> 1, wc = wid & 1;
    const int r16 = lane & 15, rg = lane >> 4;

    f32x4 acc[4][4];
#pragma unroll
    for (int i = 0; i < 4; ++i)
#pragma unroll
        for (int j = 0; j < 4; ++j)
            acc[i][j] = f32x4{0.f, 0.f, 0.f, 0.f};

    // staging: thread t covers 16B chunks (row, (t&3)*8) for row = t>>2 and t>>2 + 64
    const int srow = tid >> 2;
    const int soff = (tid & 3) * 8;
    const int nkt = K / 32;

    half8 a0, a1, b0, b1;
    {
        const f16* pa = A  + (size_t)(m0 + srow) * K + soff;
        const f16* pb = Wt + (size_t)(c0 + srow) * K + soff;
        a0 = *(const half8*)pa;
        a1 = *(const half8*)(pa + (size_t)64 * K);
        b0 = *(const half8*)pb;
        b1 = *(const half8*)(pb + (size_t)64 * K);
    }

    for (int kt = 0; kt < nkt; ++kt) {
        __syncthreads();
        *(half8*)&Ah[srow][soff]      = a0;
        *(half8*)&Ah[srow + 64][soff] = a1;
        *(half8*)&Bh[srow][soff]      = b0;
        *(half8*)&Bh[srow + 64][soff] = b1;
        __syncthreads();
        if (kt + 1 < nkt) {
            const f16* pa = A  + (size_t)(m0 + srow) * K + (kt + 1) * 32 + soff;
            const f16* pb = Wt + (size_t)(c0 + srow) * K + (kt + 1) * 32 + soff;
            a0 = *(const half8*)pa;
            a1 = *(const half8*)(pa + (size_t)64 * K);
            b0 = *(const half8*)pb;
            b1 = *(const half8*)(pb + (size_t)64 * K);
        }
        half8 af[4], bf[4];
#pragma unroll
        for (int f = 0; f < 4; ++f) {
            af[f] = *(const half8*)&Ah[wr * 64 + f * 16 + r16][rg * 8];
            bf[f] = *(const half8*)&Bh[wc * 64 + f * 16 + r16][rg * 8];
        }
#pragma unroll
        for (int fm = 0; fm < 4; ++fm)
#pragma unroll
            for (int fn = 0; fn < 4; ++fn)
                acc[fm][fn] = __builtin_amdgcn_mfma_f32_16x16x32_f16(af[fm], bf[fn], acc[fm][fn], 0, 0, 0);
    }

    // epilogue: C/D layout col=lane&15, row=(lane>>4)*4+reg
#pragma unroll
    for (int fn = 0; fn < 4; ++fn) {
        const int c = c0 + wc * 64 + fn * 16 + r16;
        const float bv = bias[c];
#pragma unroll
        for (int fm = 0; fm < 4; ++fm) {
            const int mbase = m0 + wr * 64 + fm * 16 + rg * 4;
#pragma unroll
            for (int r = 0; r < 4; ++r) {
                const float val = acc[fm][fn][r] + bv;
                const int m = mbase + r;
                if (MODE == 1) {
                    outp[(size_t)m * EDIM + c] = val;
                } else {
                    const int s  = c / EDIM;
                    const int cc = c % EDIM;
                    const int hh = cc >> 6, d = cc & 63;
                    const int bb = m >> 10, n = m & 1023;
                    f16* dst = (s == 0) ? qbuf : ((s == 1) ? kbuf : vbuf);
                    dst[(((size_t)bb * NH + hh) * NSEQ + n) * DH + d] = (f16)val;
                }
            }
        }
    }
}

// ---------------- flash attention (fp16 MFMA) ----------------
__global__ __launch_bounds__(256) void attn_kernel(
    const f16* __restrict__ qbuf, const f16* __restrict__ kbuf, const f16* __restrict__ vbuf,
    f16* __restrict__ ctx, const int* __restrict__ activep)
{
    __shared__ __align__(16) f16 Kh[64][72];
    __shared__ __align__(16) f16 Vt[64][72];   // transposed: Vt[d][k]
    __shared__ __align__(16) f16 Ps[4][16][72];

    const int b = blockIdx.z, h = blockIdx.y;
    const int q0 = blockIdx.x * 64;
    const int tid = threadIdx.x, lane = tid & 63, wid = tid >> 6;
    const int ah = *activep;

    if (h >= ah) {
        // masked head: context is exactly zero
        const int r = tid >> 2, cp = tid & 3;
        half8 z = { (f16)0,(f16)0,(f16)0,(f16)0,(f16)0,(f16)0,(f16)0,(f16)0 };
        size_t base = ((size_t)b * NSEQ + q0 + r) * EDIM + h * DH + cp * 16;
        *(half8*)&ctx[base]     = z;
        *(half8*)&ctx[base + 8] = z;
        return;
    }

    const size_t base = (((size_t)b * NH + h) * NSEQ) * DH;
    const f16* Q = qbuf + base;
    const f16* Kp = kbuf + base;
    const f16* Vp = vbuf + base;
    const int r16 = lane & 15, rg = lane >> 4;

    half8 qf0, qf1;
    {
        const int qr = q0 + wid * 16 + r16;
        qf0 = *(const half8*)&Q[(size_t)qr * DH + rg * 8];
        qf1 = *(const half8*)&Q[(size_t)qr * DH + 32 + rg * 8];
    }

    f32x4 oacc[4];
#pragma unroll
    for (int i = 0; i < 4; ++i) oacc[i] = f32x4{0.f, 0.f, 0.f, 0.f};
    float mrun[4], lrun[4];
#pragma unroll
    for (int r = 0; r < 4; ++r) { mrun[r] = -INFINITY; lrun[r] = 0.f; }

    const int krow = tid >> 3, koff = (tid & 7) * 8;   // K staging
    const int vr = tid & 63, vp = tid >> 6;            // V staging

    for (int kt = 0; kt < NSEQ / 64; ++kt) {
        const int k0 = kt * 64;
        // stage K (row-major)
        *(half8*)&Kh[krow][koff]      = *(const half8*)&Kp[(size_t)(k0 + krow) * DH + koff];
        *(half8*)&Kh[krow + 32][koff] = *(const half8*)&Kp[(size_t)(k0 + krow + 32) * DH + koff];
        // stage V transposed
        {
            half8 v0 = *(const half8*)&Vp[(size_t)(k0 + vr) * DH + vp * 16];
            half8 v1 = *(const half8*)&Vp[(size_t)(k0 + vr) * DH + vp * 16 + 8];
#pragma unroll
            for (int j = 0; j < 8; ++j) {
                Vt[vp * 16 + j][vr]     = v0[j];
                Vt[vp * 16 + 8 + j][vr] = v1[j];
            }
        }
        __syncthreads();

        // S = Q K^T  (per wave: 16 q-rows x 64 k-cols)
        f32x4 s[4];
#pragma unroll
        for (int cb = 0; cb < 4; ++cb) {
            f32x4 t = f32x4{0.f, 0.f, 0.f, 0.f};
            t = __builtin_amdgcn_mfma_f32_16x16x32_f16(qf0, *(const half8*)&Kh[cb * 16 + r16][rg * 8],      t, 0, 0, 0);
            t = __builtin_amdgcn_mfma_f32_16x16x32_f16(qf1, *(const half8*)&Kh[cb * 16 + r16][32 + rg * 8], t, 0, 0, 0);
            s[cb] = t;
        }
#pragma unroll
        for (int cb = 0; cb < 4; ++cb)
#pragma unroll
            for (int r = 0; r < 4; ++r) s[cb][r] *= 0.125f;

        // online softmax (rows replicated across each 16-lane group)
#pragma unroll
        for (int r = 0; r < 4; ++r) {
            float mx = fmaxf(fmaxf(s[0][r], s[1][r]), fmaxf(s[2][r], s[3][r]));
#pragma unroll
            for (int w = 1; w < 16; w <<= 1) mx = fmaxf(mx, __shfl_xor(mx, w));
            const float mnew = fmaxf(mrun[r], mx);
            const float sc = __expf(mrun[r] - mnew);
            float sum = 0.f;
#pragma unroll
            for (int cb = 0; cb < 4; ++cb) {
                float p = __expf(s[cb][r] - mnew);
                s[cb][r] = p;
                sum += p;
            }
#pragma unroll
            for (int w = 1; w < 16; w <<= 1) sum += __shfl_xor(sum, w);
            lrun[r] = lrun[r] * sc + sum;
            mrun[r] = mnew;
#pragma unroll
            for (int db = 0; db < 4; ++db) oacc[db][r] *= sc;
        }

        // P -> per-wave LDS (C-layout -> A-fragment layout)
#pragma unroll
        for (int cb = 0; cb < 4; ++cb)
#pragma unroll
            for (int r = 0; r < 4; ++r)
                Ps[wid][rg * 4 + r][cb * 16 + r16] = (f16)s[cb][r];

        half8 pa0 = *(const half8*)&Ps[wid][r16][rg * 8];
        half8 pa1 = *(const half8*)&Ps[wid][r16][32 + rg * 8];
#pragma unroll
        for (int db = 0; db < 4; ++db) {
            oacc[db] = __builtin_amdgcn_mfma_f32_16x16x32_f16(pa0, *(const half8*)&Vt[db * 16 + r16][rg * 8],      oacc[db], 0, 0, 0);
            oacc[db] = __builtin_amdgcn_mfma_f32_16x16x32_f16(pa1, *(const half8*)&Vt[db * 16 + r16][32 + rg * 8], oacc[db], 0, 0, 0);
        }
        __syncthreads();
    }

    // epilogue: normalize, store ctx fp16
#pragma unroll
    for (int r = 0; r < 4; ++r) {
        const float inv = 1.0f / lrun[r];
        const int n = q0 + wid * 16 + rg * 4 + r;
#pragma unroll
        for (int db = 0; db < 4; ++db)
            ctx[((size_t)b * NSEQ + n) * EDIM + h * DH + db * 16 + r16] = (f16)(oacc[db][r] * inv);
    }
}

// ---------------- launch ----------------
extern "C" void kernel_launch(void* const* d_in, const int* in_sizes, int n_in,
                              void* d_out, int out_size, void* d_ws, size_t ws_size,
                              hipStream_t stream) {
    const float* x      = (const float*)d_in[0];
    const float* w_qkv  = (const float*)d_in[1];
    const float* b_qkv  = (const float*)d_in[2];
    const float* w_proj = (const float*)d_in[3];
    const float* b_proj = (const float*)d_in[4];
    const int*   active = (const int*)d_in[5];
    float* out = (float*)d_out;

    char* ws = (char*)d_ws;
    const size_t n_x  = (size_t)BSZ * NSEQ * EDIM;       // 6291456
    const size_t n_wq = (size_t)3 * EDIM * EDIM;         // 1769472
    const size_t n_wp = (size_t)EDIM * EDIM;             // 589824
    const size_t n_hd = (size_t)BSZ * NH * NSEQ * DH;    // 6291456 per q/k/v

    f16* xh   = (f16*)ws;
    f16* wqh  = xh + n_x;
    f16* wph  = wqh + n_wq;
    f16* qh   = wph + n_wp;
    f16* kh   = qh + n_hd;
    f16* vh   = kh + n_hd;
    f16* ctxh = vh + n_hd;
    // total = (6291456 + 1769472 + 589824 + 3*6291456 + 6291456)*2 bytes ~= 64.5 MB

    cvt_kernel<<<(int)(n_x  / 4 / 256), 256, 0, stream>>>(x, xh, (int)n_x);
    cvt_kernel<<<(int)(n_wq / 4 / 256), 256, 0, stream>>>(w_qkv, wqh, (int)n_wq);
    cvt_kernel<<<(int)(n_wp / 4 / 256), 256, 0, stream>>>(w_proj, wph, (int)n_wp);

    gemm_kernel<0><<<dim3(3 * EDIM / 128, BSZ * NSEQ / 128), 256, 0, stream>>>(
        xh, wqh, b_qkv, qh, kh, vh, nullptr, active, EDIM, 3 * EDIM);

    attn_kernel<<<dim3(NSEQ / 64, NH, BSZ), 256, 0, stream>>>(qh, kh, vh, ctxh, active);

    gemm_kernel<1><<<dim3(EDIM / 128, BSZ * NSEQ / 128), 256, 0, stream>>>(
        ctxh, wph, b_proj, nullptr, nullptr, nullptr, out, active, EDIM, EDIM);
}

// Round 2
// 132.306 us; speedup vs baseline: 1.1211x; 1.1211x over previous
//
#include <hip/hip_runtime.h>
#include <hip/hip_fp16.h>

#define NH 12
#define BSZ 8
#define NSEQ 1024
#define EDIM 768
#define DH 64

typedef _Float16 f16;
typedef f16 half8 __attribute__((ext_vector_type(8)));
typedef f16 half4 __attribute__((ext_vector_type(4)));
typedef float f32x4 __attribute__((ext_vector_type(4)));
typedef unsigned int u32;
typedef u32 u32x4 __attribute__((ext_vector_type(4)));

static __device__ __forceinline__ void gload16(const void* g, void* l) {
    __builtin_amdgcn_global_load_lds((const __attribute__((address_space(1))) u32*)g,
                                     (__attribute__((address_space(3))) u32*)l, 16, 0, 0);
}
static __device__ __forceinline__ u32 pkrtz(float a, float b) {
    auto h = __builtin_amdgcn_cvt_pkrtz(a, b);
    return __builtin_bit_cast(u32, h);
}
#define SHFU(v, s) ((u32)__shfl((int)(v), (s)))
#define MFMA16(a, b, c) __builtin_amdgcn_mfma_f32_16x16x32_f16((a), (b), (c), 0, 0, 0)

// ---------------- fused fp32 -> fp16 convert (x | w_qkv | w_proj) ----------------
__global__ void cvt_all_kernel(const float* __restrict__ x, const float* __restrict__ wq,
                               const float* __restrict__ wp, f16* __restrict__ dst) {
    const int NX = BSZ * NSEQ * EDIM;
    const int NWQ = 3 * EDIM * EDIM;
    int i = (blockIdx.x * blockDim.x + threadIdx.x) * 4;
    const float* s;
    int j;
    if (i < NX) { s = x; j = i; }
    else if (i < NX + NWQ) { s = wq; j = i - NX; }
    else { s = wp; j = i - NX - NWQ; }
    float4 v = *(const float4*)(s + j);
    half4 o = { (f16)v.x, (f16)v.y, (f16)v.z, (f16)v.w };
    *(half4*)(dst + i) = o;
}

// ---------------- GEMM: C[m][c] = sum_k A[m][k]*W[c][k] + bias[c] ----------------
// global_load_lds staging, double-buffered, one barrier per K-step.
template<int MODE>
__global__ __launch_bounds__(256) void gemm_kernel(
    const f16* __restrict__ A, const f16* __restrict__ Wt, const float* __restrict__ bias,
    f16* __restrict__ qbuf, f16* __restrict__ kbuf, f16* __restrict__ vbuf,
    float* __restrict__ outp, const int* __restrict__ activep, int K, int NC)
{
    __shared__ __align__(16) f16 Ah[2][128][32];
    __shared__ __align__(16) f16 Bh[2][128][32];

    const int tid = threadIdx.x;
    const int c0 = blockIdx.x * 128;
    const int m0 = blockIdx.y * 128;
    if (MODE == 0) {
        int hb = (c0 % EDIM) >> 6;
        if (hb >= *activep) return;   // both heads masked -> qkv never read
    }
    const int lane = tid & 63;
    const int wid  = tid >> 6;
    const int wr = wid >> 1, wc = wid & 1;
    const int r16 = lane & 15, rg = lane >> 4;

    f32x4 acc[4][4];
#pragma unroll
    for (int i = 0; i < 4; ++i)
#pragma unroll
        for (int j = 0; j < 4; ++j)
            acc[i][j] = f32x4{0.f, 0.f, 0.f, 0.f};

    // staging: each wave covers 32 rows (2 instrs of 16 rows) of A and of B
    const int srow = wid * 32 + (lane >> 2);
    const int scol = (lane & 3) * 8;
    const f16* gA = A  + (size_t)(m0 + srow) * K + scol;
    const f16* gB = Wt + (size_t)(c0 + srow) * K + scol;
    const int nkt = K / 32;

    auto stage = [&](int buf, int kt) {
        const f16* a0 = gA + kt * 32;
        const f16* b0 = gB + kt * 32;
        gload16(a0,                  &Ah[buf][wid * 32][0]);
        gload16(a0 + (size_t)16 * K, &Ah[buf][wid * 32 + 16][0]);
        gload16(b0,                  &Bh[buf][wid * 32][0]);
        gload16(b0 + (size_t)16 * K, &Bh[buf][wid * 32 + 16][0]);
    };

    stage(0, 0);
    __syncthreads();
    int cur = 0;
    for (int kt = 0; kt < nkt; ++kt) {
        if (kt + 1 < nkt) stage(cur ^ 1, kt + 1);   // loads fly during MFMA below
        half8 af[4], bf[4];
#pragma unroll
        for (int f = 0; f < 4; ++f) {
            af[f] = *(const half8*)&Ah[cur][wr * 64 + f * 16 + r16][rg * 8];
            bf[f] = *(const half8*)&Bh[cur][wc * 64 + f * 16 + r16][rg * 8];
        }
#pragma unroll
        for (int fm = 0; fm < 4; ++fm)
#pragma unroll
            for (int fn = 0; fn < 4; ++fn)
                acc[fm][fn] = MFMA16(af[fm], bf[fn], acc[fm][fn]);
        __syncthreads();   // drains vmcnt: next buffer ready
        cur ^= 1;
    }

    // epilogue: C/D layout col=lane&15, row=(lane>>4)*4+reg
#pragma unroll
    for (int fn = 0; fn < 4; ++fn) {
        const int c = c0 + wc * 64 + fn * 16 + r16;
        const float bv = bias[c];
#pragma unroll
        for (int fm = 0; fm < 4; ++fm) {
            const int mbase = m0 + wr * 64 + fm * 16 + rg * 4;
#pragma unroll
            for (int r = 0; r < 4; ++r) {
                const float val = acc[fm][fn][r] + bv;
                const int m = mbase + r;
                if (MODE == 1) {
                    outp[(size_t)m * EDIM + c] = val;
                } else {
                    const int s  = c / EDIM;
                    const int cc = c % EDIM;
                    const int hh = cc >> 6, d = cc & 63;
                    const int bb = m >> 10, n = m & 1023;
                    f16* dst = (s == 0) ? qbuf : ((s == 1) ? kbuf : vbuf);
                    dst[(((size_t)bb * NH + hh) * NSEQ + n) * DH + d] = (f16)val;
                }
            }
        }
    }
}

// ---------------- flash attention: swapped QK^T, in-register softmax ----------------
__global__ __launch_bounds__(256) void attn_kernel(
    const f16* __restrict__ qbuf, const f16* __restrict__ kbuf, const f16* __restrict__ vbuf,
    f16* __restrict__ ctx, const int* __restrict__ activep)
{
    __shared__ __align__(16) f16 Kh[2][64][72];
    __shared__ __align__(16) f16 Vt[2][64][72];   // Vt[d][k]

    const int b = blockIdx.z, h = blockIdx.y;
    const int q0 = blockIdx.x * 64;
    const int tid = threadIdx.x, lane = tid & 63, wid = tid >> 6;

    if (h >= *activep) {
        const int r = tid >> 2, cp = tid & 3;
        half8 z = { (f16)0,(f16)0,(f16)0,(f16)0,(f16)0,(f16)0,(f16)0,(f16)0 };
        size_t base = ((size_t)b * NSEQ + q0 + r) * EDIM + h * DH + cp * 16;
        *(half8*)&ctx[base]     = z;
        *(half8*)&ctx[base + 8] = z;
        return;
    }

    const size_t hb = (((size_t)b * NH + h) * NSEQ) * DH;
    const f16* Q  = qbuf + hb;
    const f16* Kp = kbuf + hb;
    const f16* Vp = vbuf + hb;

    const int ql = lane & 15;   // this lane's q-row (softmax owner) / d-col (PV)
    const int g  = lane >> 4;   // lane group

    // Q B-fragment, pre-scaled by 1/8 (exact in f16)
    half8 qb0, qb1;
    {
        const f16* qp = Q + (size_t)(q0 + wid * 16 + ql) * DH + g * 8;
        qb0 = *(const half8*)qp        * (f16)0.125f;
        qb1 = *(const half8*)(qp + 32) * (f16)0.125f;
    }

    // staging maps
    const int krow = tid >> 2, kcol = (tid & 3) * 16;
    const f16* gK = Kp + (size_t)krow * DH + kcol;
    const f16* gV = Vp + (size_t)lane * DH + wid * 16;

    half8 kr0, kr1, vv0, vv1;
    auto loadT = [&](int kt) {
        const f16* pk = gK + (size_t)kt * 64 * DH;
        kr0 = *(const half8*)pk;
        kr1 = *(const half8*)(pk + 8);
        const f16* pv = gV + (size_t)kt * 64 * DH;
        vv0 = *(const half8*)pv;
        vv1 = *(const half8*)(pv + 8);
    };
    auto storeT = [&](int buf) {
        *(half8*)&Kh[buf][krow][kcol]     = kr0;
        *(half8*)&Kh[buf][krow][kcol + 8] = kr1;
#pragma unroll
        for (int j = 0; j < 8; ++j) {
            Vt[buf][wid * 16 + j][lane]     = vv0[j];
            Vt[buf][wid * 16 + 8 + j][lane] = vv1[j];
        }
    };

    loadT(0);
    storeT(0);

    f32x4 oacc[4];
#pragma unroll
    for (int i = 0; i < 4; ++i) oacc[i] = f32x4{0.f, 0.f, 0.f, 0.f};
    float mr = -INFINITY, lr = 0.f;

    const int src0 = ql + ((lane & 16) << 1);  // ql + 32*(g&1)
    const int src1 = src0 + 16;
    const bool hi = (lane >= 32);              // selects upper k-sub pair

    for (int kt = 0; kt < NSEQ / 64; ++kt) {
        const int cur = kt & 1;
        if (kt + 1 < NSEQ / 64) loadT(kt + 1);   // global loads overlap barrier+compute
        __syncthreads();

        // S^T tile: st[s] holds S^T[k = s*16 + g*4 + r][q = ql]  (pre-scaled by 1/8)
        f32x4 st[4];
#pragma unroll
        for (int s = 0; s < 4; ++s) {
            f32x4 t = f32x4{0.f, 0.f, 0.f, 0.f};
            t = MFMA16(*(const half8*)&Kh[cur][s * 16 + ql][g * 8],      qb0, t);
            t = MFMA16(*(const half8*)&Kh[cur][s * 16 + ql][32 + g * 8], qb1, t);
            st[s] = t;
        }

        // online softmax: lane owns q-row ql; reduce over lanes ql, ql+16, ql+32, ql+48
        float pmax;
        {
            float m0v = fmaxf(fmaxf(st[0][0], st[0][1]), fmaxf(st[0][2], st[0][3]));
            float m1v = fmaxf(fmaxf(st[1][0], st[1][1]), fmaxf(st[1][2], st[1][3]));
            float m2v = fmaxf(fmaxf(st[2][0], st[2][1]), fmaxf(st[2][2], st[2][3]));
            float m3v = fmaxf(fmaxf(st[3][0], st[3][1]), fmaxf(st[3][2], st[3][3]));
            pmax = fmaxf(fmaxf(m0v, m1v), fmaxf(m2v, m3v));
        }
        pmax = fmaxf(pmax, __shfl_xor(pmax, 16));
        pmax = fmaxf(pmax, __shfl_xor(pmax, 32));
        const float mnew = fmaxf(mr, pmax);
        const float sc = __expf(mr - mnew);
        float psum = 0.f;
#pragma unroll
        for (int s = 0; s < 4; ++s)
#pragma unroll
            for (int r = 0; r < 4; ++r) {
                float p = __expf(st[s][r] - mnew);
                st[s][r] = p;
                psum += p;
            }
        psum += __shfl_xor(psum, 16);
        psum += __shfl_xor(psum, 32);
        lr = lr * sc + psum;
        mr = mnew;

        // rescale O accumulator (rows of C are q = g*4 + r; fetch that row's factor)
#pragma unroll
        for (int r = 0; r < 4; ++r) {
            const float scr = __shfl(sc, (g << 2) | r);
            oacc[0][r] *= scr; oacc[1][r] *= scr; oacc[2][r] *= scr; oacc[3][r] *= scr;
        }

        // pack P to f16 pairs: w{s}{p} = (k = s*16+g*4+2p, +1) for q=ql
        const u32 w00 = pkrtz(st[0][0], st[0][1]), w01 = pkrtz(st[0][2], st[0][3]);
        const u32 w10 = pkrtz(st[1][0], st[1][1]), w11 = pkrtz(st[1][2], st[1][3]);
        const u32 w20 = pkrtz(st[2][0], st[2][1]), w21 = pkrtz(st[2][2], st[2][3]);
        const u32 w30 = pkrtz(st[3][0], st[3][1]), w31 = pkrtz(st[3][2], st[3][3]);

        // redistribute to A-fragment layout: lane needs P[q=ql][k = m*32 + g*8 + j]
        u32x4 pa0, pa1;
        {
            u32 a, bb2;
            a = SHFU(w00, src0); bb2 = SHFU(w10, src0); pa0[0] = hi ? bb2 : a;
            a = SHFU(w01, src0); bb2 = SHFU(w11, src0); pa0[1] = hi ? bb2 : a;
            a = SHFU(w00, src1); bb2 = SHFU(w10, src1); pa0[2] = hi ? bb2 : a;
            a = SHFU(w01, src1); bb2 = SHFU(w11, src1); pa0[3] = hi ? bb2 : a;
            a = SHFU(w20, src0); bb2 = SHFU(w30, src0); pa1[0] = hi ? bb2 : a;
            a = SHFU(w21, src0); bb2 = SHFU(w31, src0); pa1[1] = hi ? bb2 : a;
            a = SHFU(w20, src1); bb2 = SHFU(w30, src1); pa1[2] = hi ? bb2 : a;
            a = SHFU(w21, src1); bb2 = SHFU(w31, src1); pa1[3] = hi ? bb2 : a;
        }
        const half8 pah0 = __builtin_bit_cast(half8, pa0);
        const half8 pah1 = __builtin_bit_cast(half8, pa1);

        // O += P V : A-frag = P (rows q), B-frag = V (cols d) read from Vt[d][k]
#pragma unroll
        for (int db = 0; db < 4; ++db) {
            oacc[db] = MFMA16(pah0, *(const half8*)&Vt[cur][db * 16 + ql][g * 8],      oacc[db]);
            oacc[db] = MFMA16(pah1, *(const half8*)&Vt[cur][db * 16 + ql][32 + g * 8], oacc[db]);
        }

        if (kt + 1 < NSEQ / 64) storeT(cur ^ 1);   // write next tile (other buffer)
    }

    // epilogue: rows q = g*4 + r, cols d = db*16 + ql
#pragma unroll
    for (int r = 0; r < 4; ++r) {
        const float li = 1.0f / __shfl(lr, (g << 2) | r);
        const int n = q0 + wid * 16 + (g << 2) + r;
#pragma unroll
        for (int db = 0; db < 4; ++db)
            ctx[((size_t)b * NSEQ + n) * EDIM + h * DH + db * 16 + ql] = (f16)(oacc[db][r] * li);
    }
}

// ---------------- launch ----------------
extern "C" void kernel_launch(void* const* d_in, const int* in_sizes, int n_in,
                              void* d_out, int out_size, void* d_ws, size_t ws_size,
                              hipStream_t stream) {
    const float* x      = (const float*)d_in[0];
    const float* w_qkv  = (const float*)d_in[1];
    const float* b_qkv  = (const float*)d_in[2];
    const float* w_proj = (const float*)d_in[3];
    const float* b_proj = (const float*)d_in[4];
    const int*   active = (const int*)d_in[5];
    float* out = (float*)d_out;

    char* ws = (char*)d_ws;
    const size_t n_x  = (size_t)BSZ * NSEQ * EDIM;       // 6291456
    const size_t n_wq = (size_t)3 * EDIM * EDIM;         // 1769472
    const size_t n_wp = (size_t)EDIM * EDIM;             // 589824
    const size_t n_hd = (size_t)BSZ * NH * NSEQ * DH;    // 6291456 per q/k/v

    f16* xh   = (f16*)ws;
    f16* wqh  = xh + n_x;
    f16* wph  = wqh + n_wq;
    f16* qh   = wph + n_wp;
    f16* kh   = qh + n_hd;
    f16* vh   = kh + n_hd;
    f16* ctxh = vh + n_hd;

    const size_t n_cvt = n_x + n_wq + n_wp;   // 8650752, divisible by 1024
    cvt_all_kernel<<<(int)(n_cvt / 4 / 256), 256, 0, stream>>>(x, w_qkv, w_proj, xh);

    gemm_kernel<0><<<dim3(3 * EDIM / 128, BSZ * NSEQ / 128), 256, 0, stream>>>(
        xh, wqh, b_qkv, qh, kh, vh, nullptr, active, EDIM, 3 * EDIM);

    attn_kernel<<<dim3(NSEQ / 64, NH, BSZ), 256, 0, stream>>>(qh, kh, vh, ctxh, active);

    gemm_kernel<1><<<dim3(EDIM / 128, BSZ * NSEQ / 128), 256, 0, stream>>>(
        ctxh, wph, b_proj, nullptr, nullptr, nullptr, out, active, EDIM, EDIM);
}

// Round 3
// 129.233 us; speedup vs baseline: 1.1478x; 1.0238x over previous
//
#include <hip/hip_runtime.h>
#include <hip/hip_fp16.h>

#define NH 12
#define BSZ 8
#define NSEQ 1024
#define EDIM 768
#define DH 64

typedef _Float16 f16;
typedef f16 half8 __attribute__((ext_vector_type(8)));
typedef f16 half4 __attribute__((ext_vector_type(4)));
typedef float f32x4 __attribute__((ext_vector_type(4)));
typedef unsigned int u32;
typedef u32 u32x2 __attribute__((ext_vector_type(2)));

static __device__ __forceinline__ void gload16(const void* g, void* l) {
    __builtin_amdgcn_global_load_lds((const __attribute__((address_space(1))) u32*)g,
                                     (__attribute__((address_space(3))) u32*)l, 16, 0, 0);
}
static __device__ __forceinline__ u32 pkrtz(float a, float b) {
    auto h = __builtin_amdgcn_cvt_pkrtz(a, b);
    return __builtin_bit_cast(u32, h);
}
#define MFMA16(a, b, c) __builtin_amdgcn_mfma_f32_16x16x32_f16((a), (b), (c), 0, 0, 0)

// ---------------- fused fp32 -> fp16 convert (x | w_qkv | w_proj) ----------------
__global__ void cvt_all_kernel(const float* __restrict__ x, const float* __restrict__ wq,
                               const float* __restrict__ wp, f16* __restrict__ dst) {
    const int NX = BSZ * NSEQ * EDIM;
    const int NWQ = 3 * EDIM * EDIM;
    int i = (blockIdx.x * blockDim.x + threadIdx.x) * 4;
    const float* s;
    int j;
    if (i < NX) { s = x; j = i; }
    else if (i < NX + NWQ) { s = wq; j = i - NX; }
    else { s = wp; j = i - NX - NWQ; }
    float4 v = *(const float4*)(s + j);
    half4 o = { (f16)v.x, (f16)v.y, (f16)v.z, (f16)v.w };
    *(half4*)(dst + i) = o;
}

// ---------------- GEMM: C[m][c] = sum_k A[m][k]*W[c][k] + bias[c] ----------------
template<int MODE>
__global__ __launch_bounds__(256) void gemm_kernel(
    const f16* __restrict__ A, const f16* __restrict__ Wt, const float* __restrict__ bias,
    f16* __restrict__ qbuf, f16* __restrict__ kbuf, f16* __restrict__ vbuf,
    float* __restrict__ outp, const int* __restrict__ activep, int K, int NC)
{
    __shared__ __align__(16) f16 Ah[2][128][32];
    __shared__ __align__(16) f16 Bh[2][128][32];

    const int tid = threadIdx.x;
    const int c0 = blockIdx.x * 128;
    const int m0 = blockIdx.y * 128;
    if (MODE == 0) {
        int hb = (c0 % EDIM) >> 6;
        if (hb >= *activep) return;   // both heads masked -> qkv never read
    }
    const int lane = tid & 63;
    const int wid  = tid >> 6;
    const int wr = wid >> 1, wc = wid & 1;
    const int r16 = lane & 15, rg = lane >> 4;

    f32x4 acc[4][4];
#pragma unroll
    for (int i = 0; i < 4; ++i)
#pragma unroll
        for (int j = 0; j < 4; ++j)
            acc[i][j] = f32x4{0.f, 0.f, 0.f, 0.f};

    const int srow = wid * 32 + (lane >> 2);
    const int scol = (lane & 3) * 8;
    const f16* gA = A  + (size_t)(m0 + srow) * K + scol;
    const f16* gB = Wt + (size_t)(c0 + srow) * K + scol;
    const int nkt = K / 32;

    auto stage = [&](int buf, int kt) {
        const f16* a0 = gA + kt * 32;
        const f16* b0 = gB + kt * 32;
        gload16(a0,                  &Ah[buf][wid * 32][0]);
        gload16(a0 + (size_t)16 * K, &Ah[buf][wid * 32 + 16][0]);
        gload16(b0,                  &Bh[buf][wid * 32][0]);
        gload16(b0 + (size_t)16 * K, &Bh[buf][wid * 32 + 16][0]);
    };

    stage(0, 0);
    __syncthreads();
    int cur = 0;
    for (int kt = 0; kt < nkt; ++kt) {
        if (kt + 1 < nkt) stage(cur ^ 1, kt + 1);
        half8 af[4], bf[4];
#pragma unroll
        for (int f = 0; f < 4; ++f) {
            af[f] = *(const half8*)&Ah[cur][wr * 64 + f * 16 + r16][rg * 8];
            bf[f] = *(const half8*)&Bh[cur][wc * 64 + f * 16 + r16][rg * 8];
        }
#pragma unroll
        for (int fm = 0; fm < 4; ++fm)
#pragma unroll
            for (int fn = 0; fn < 4; ++fn)
                acc[fm][fn] = MFMA16(af[fm], bf[fn], acc[fm][fn]);
        __syncthreads();
        cur ^= 1;
    }

#pragma unroll
    for (int fn = 0; fn < 4; ++fn) {
        const int c = c0 + wc * 64 + fn * 16 + r16;
        const float bv = bias[c];
#pragma unroll
        for (int fm = 0; fm < 4; ++fm) {
            const int mbase = m0 + wr * 64 + fm * 16 + rg * 4;
#pragma unroll
            for (int r = 0; r < 4; ++r) {
                const float val = acc[fm][fn][r] + bv;
                const int m = mbase + r;
                if (MODE == 1) {
                    outp[(size_t)m * EDIM + c] = val;
                } else {
                    const int s  = c / EDIM;
                    const int cc = c % EDIM;
                    const int hh = cc >> 6, d = cc & 63;
                    const int bb = m >> 10, n = m & 1023;
                    f16* dst = (s == 0) ? qbuf : ((s == 1) ? kbuf : vbuf);
                    dst[(((size_t)bb * NH + hh) * NSEQ + n) * DH + d] = (f16)val;
                }
            }
        }
    }
}

// ---------------- V transpose: vbuf [b][h][n][d] -> vtb [b][h][d][n] ----------------
__global__ __launch_bounds__(256) void vtrans_kernel(const f16* __restrict__ vbuf,
                                                     f16* __restrict__ vtb,
                                                     const int* __restrict__ activep) {
    const int b = blockIdx.z, h = blockIdx.y;
    if (h >= *activep) return;
    const int n0 = blockIdx.x * 64;
    __shared__ __align__(16) f16 T[64][72];
    const f16* src = vbuf + (((size_t)b * NH + h) * NSEQ + n0) * DH;
    f16* dst = vtb + ((size_t)b * NH + h) * DH * NSEQ;
    const int t = threadIdx.x;
    const int rn = t >> 2, rc = t & 3;
    *(half8*)&T[rn][rc * 16]     = *(const half8*)&src[(size_t)rn * DH + rc * 16];
    *(half8*)&T[rn][rc * 16 + 8] = *(const half8*)&src[(size_t)rn * DH + rc * 16 + 8];
    __syncthreads();
    const int d = t >> 2, nc = (t & 3) * 16;
    half8 o0, o1;
#pragma unroll
    for (int j = 0; j < 8; ++j) {
        o0[j] = T[nc + j][d];
        o1[j] = T[nc + 8 + j][d];
    }
    *(half8*)&dst[(size_t)d * NSEQ + n0 + nc]     = o0;
    *(half8*)&dst[(size_t)d * NSEQ + n0 + nc + 8] = o1;
}

// ---------------- flash attention: gload_lds K/V^T, swizzled LDS, P via LDS ----------------
__global__ __launch_bounds__(256) void attn_kernel(
    const f16* __restrict__ qbuf, const f16* __restrict__ kbuf, const f16* __restrict__ vtb,
    f16* __restrict__ ctx, const int* __restrict__ activep)
{
    __shared__ __align__(16) f16 Kh[2][64][64];
    __shared__ __align__(16) f16 Vh[2][64][64];   // swizzled V^T tile: row d, 64 k
    __shared__ __align__(16) f16 Ph[4][16][64];   // per-wave P, swizzled

    const int b = blockIdx.z, h = blockIdx.y;
    const int q0 = blockIdx.x * 64;
    const int tid = threadIdx.x, lane = tid & 63, wid = tid >> 6;

    if (h >= *activep) {
        const int r = tid >> 2, cp = tid & 3;
        half8 z = { (f16)0,(f16)0,(f16)0,(f16)0,(f16)0,(f16)0,(f16)0,(f16)0 };
        size_t base = ((size_t)b * NSEQ + q0 + r) * EDIM + h * DH + cp * 16;
        *(half8*)&ctx[base]     = z;
        *(half8*)&ctx[base + 8] = z;
        return;
    }

    const size_t hb = (((size_t)b * NH + h) * NSEQ) * DH;
    const f16* Q  = qbuf + hb;
    const char* Kp = (const char*)(kbuf + hb);
    const char* Vp = (const char*)(vtb + hb);   // rows d, stride NSEQ*2 bytes

    const int ql = lane & 15;
    const int g  = lane >> 4;
    const int q7 = ql & 7;

    // Q B-fragment, pre-scaled by 1/8 (exact in f16)
    half8 qb0, qb1;
    {
        const f16* qp = Q + (size_t)(q0 + wid * 16 + ql) * DH + g * 8;
        qb0 = *(const half8*)qp        * (f16)0.125f;
        qb1 = *(const half8*)(qp + 32) * (f16)0.125f;
    }

    // gload_lds staging with pre-swizzled global source (chunk ^= row&7)
    const int srow8 = lane >> 3;                 // row within 8-row group
    const int schk  = (lane & 7) ^ srow8;        // swizzled source chunk

    auto stage = [&](int buf, int kt) {
        const char* kb = Kp + (size_t)kt * 8192;            // 64 rows * 128B
#pragma unroll
        for (int i = 0; i < 2; ++i) {
            const int r = wid * 16 + i * 8 + srow8;
            gload16(kb + (size_t)r * 128 + schk * 16, &Kh[buf][wid * 16 + i * 8][0]);
            gload16(Vp + (size_t)r * (NSEQ * 2) + (size_t)kt * 128 + schk * 16,
                    &Vh[buf][wid * 16 + i * 8][0]);
        }
    };

    f32x4 oacc[4];
#pragma unroll
    for (int i = 0; i < 4; ++i) oacc[i] = f32x4{0.f, 0.f, 0.f, 0.f};
    float mr = -INFINITY, lr = 0.f;

    char* prow = (char*)&Ph[wid][ql][0];

    stage(0, 0);
    const int NT = NSEQ / 64;
    for (int kt = 0; kt < NT; ++kt) {
        const int cur = kt & 1;
        __syncthreads();                     // cur's loads landed; prev reads done
        if (kt + 1 < NT) stage(cur ^ 1, kt + 1);   // fly during compute below

        // S^T = K Q^T : st[s][r] = S^T[k=16s+4g+r][q=ql]
        f32x4 st[4];
        __builtin_amdgcn_s_setprio(1);
#pragma unroll
        for (int s = 0; s < 4; ++s) {
            f32x4 t = f32x4{0.f, 0.f, 0.f, 0.f};
            t = MFMA16(*(const half8*)((const char*)&Kh[cur][16 * s + ql][0] + ((g ^ q7) << 4)),       qb0, t);
            t = MFMA16(*(const half8*)((const char*)&Kh[cur][16 * s + ql][0] + (((4 | g) ^ q7) << 4)), qb1, t);
            st[s] = t;
        }
        __builtin_amdgcn_s_setprio(0);

        // online softmax (state replicated across lanes ql, ql+16, ql+32, ql+48)
        float pmax;
        {
            float m0v = fmaxf(fmaxf(st[0][0], st[0][1]), fmaxf(st[0][2], st[0][3]));
            float m1v = fmaxf(fmaxf(st[1][0], st[1][1]), fmaxf(st[1][2], st[1][3]));
            float m2v = fmaxf(fmaxf(st[2][0], st[2][1]), fmaxf(st[2][2], st[2][3]));
            float m3v = fmaxf(fmaxf(st[3][0], st[3][1]), fmaxf(st[3][2], st[3][3]));
            pmax = fmaxf(fmaxf(m0v, m1v), fmaxf(m2v, m3v));
        }
        pmax = fmaxf(pmax, __shfl_xor(pmax, 16));
        pmax = fmaxf(pmax, __shfl_xor(pmax, 32));
        const float mnew = fmaxf(mr, pmax);
        const float sc = __expf(mr - mnew);
        float psum = 0.f;
#pragma unroll
        for (int s = 0; s < 4; ++s)
#pragma unroll
            for (int r = 0; r < 4; ++r) {
                float p = __expf(st[s][r] - mnew);
                st[s][r] = p;
                psum += p;
            }
        psum += __shfl_xor(psum, 16);
        psum += __shfl_xor(psum, 32);
        lr = lr * sc + psum;
        mr = mnew;

        // rescale O accumulator (C rows are q = 4g + r)
#pragma unroll
        for (int r = 0; r < 4; ++r) {
            const float scr = __shfl(sc, (g << 2) | r);
            oacc[0][r] *= scr; oacc[1][r] *= scr; oacc[2][r] *= scr; oacc[3][r] *= scr;
        }

        // P -> per-wave swizzled LDS: row ql, halves k = 16s+4g .. +3
#pragma unroll
        for (int s = 0; s < 4; ++s) {
            u32x2 w = { pkrtz(st[s][0], st[s][1]), pkrtz(st[s][2], st[s][3]) };
            *(u32x2*)(prow + ((32 * s + 8 * g) ^ (q7 << 4))) = w;
        }
        const half8 pa0 = *(const half8*)(prow + ((16 * g) ^ (q7 << 4)));
        const half8 pa1 = *(const half8*)(prow + ((64 + 16 * g) ^ (q7 << 4)));

        // O += P V : B-frag from Vh[d][k] (swizzled)
        __builtin_amdgcn_s_setprio(1);
#pragma unroll
        for (int db = 0; db < 4; ++db) {
            oacc[db] = MFMA16(pa0, *(const half8*)((const char*)&Vh[cur][16 * db + ql][0] + ((g ^ q7) << 4)),       oacc[db]);
            oacc[db] = MFMA16(pa1, *(const half8*)((const char*)&Vh[cur][16 * db + ql][0] + (((4 | g) ^ q7) << 4)), oacc[db]);
        }
        __builtin_amdgcn_s_setprio(0);
    }

    // epilogue: rows q = 4g + r, cols d = db*16 + ql
#pragma unroll
    for (int r = 0; r < 4; ++r) {
        const float li = 1.0f / __shfl(lr, (g << 2) | r);
        const int n = q0 + wid * 16 + (g << 2) + r;
#pragma unroll
        for (int db = 0; db < 4; ++db)
            ctx[((size_t)b * NSEQ + n) * EDIM + h * DH + db * 16 + ql] = (f16)(oacc[db][r] * li);
    }
}

// ---------------- launch ----------------
extern "C" void kernel_launch(void* const* d_in, const int* in_sizes, int n_in,
                              void* d_out, int out_size, void* d_ws, size_t ws_size,
                              hipStream_t stream) {
    const float* x      = (const float*)d_in[0];
    const float* w_qkv  = (const float*)d_in[1];
    const float* b_qkv  = (const float*)d_in[2];
    const float* w_proj = (const float*)d_in[3];
    const float* b_proj = (const float*)d_in[4];
    const int*   active = (const int*)d_in[5];
    float* out = (float*)d_out;

    char* ws = (char*)d_ws;
    const size_t n_x  = (size_t)BSZ * NSEQ * EDIM;       // 6291456
    const size_t n_wq = (size_t)3 * EDIM * EDIM;         // 1769472
    const size_t n_wp = (size_t)EDIM * EDIM;             // 589824
    const size_t n_hd = (size_t)BSZ * NH * NSEQ * DH;    // 6291456 per q/k/v

    f16* xh   = (f16*)ws;
    f16* wqh  = xh + n_x;
    f16* wph  = wqh + n_wq;
    f16* qh   = wph + n_wp;
    f16* kh   = qh + n_hd;
    f16* vh   = kh + n_hd;
    f16* ctxh = vh + n_hd;
    f16* vtb  = xh;   // alias: xh is dead after gemm<0>; n_x == n_hd

    const size_t n_cvt = n_x + n_wq + n_wp;
    cvt_all_kernel<<<(int)(n_cvt / 4 / 256), 256, 0, stream>>>(x, w_qkv, w_proj, xh);

    gemm_kernel<0><<<dim3(3 * EDIM / 128, BSZ * NSEQ / 128), 256, 0, stream>>>(
        xh, wqh, b_qkv, qh, kh, vh, nullptr, active, EDIM, 3 * EDIM);

    vtrans_kernel<<<dim3(NSEQ / 64, NH, BSZ), 256, 0, stream>>>(vh, vtb, active);

    attn_kernel<<<dim3(NSEQ / 64, NH, BSZ), 256, 0, stream>>>(qh, kh, vtb, ctxh, active);

    gemm_kernel<1><<<dim3(EDIM / 128, BSZ * NSEQ / 128), 256, 0, stream>>>(
        ctxh, wph, b_proj, nullptr, nullptr, nullptr, out, active, EDIM, EDIM);
}